// Round 14
// baseline (274.938 us; speedup 1.0000x reference)
//
#include <hip/hip_runtime.h>
#include <cstddef>

#define NT 100000
#define NN1 40000
#define NN2 30000
#define NN3 30000
#define EE 800000

typedef _Float16 f16;
typedef f16 f16x8 __attribute__((ext_vector_type(8)));
typedef f16 f16x4 __attribute__((ext_vector_type(4)));
typedef float f32x4 __attribute__((ext_vector_type(4)));

static inline int cdiv(int a, int b) { return (a + b - 1) / b; }

// async global->LDS, 16B per lane
__device__ __forceinline__ void gload_lds16(const f16* g, f16* l) {
    __builtin_amdgcn_global_load_lds(
        (const __attribute__((address_space(1))) void*)g,
        (__attribute__((address_space(3))) void*)l, 16, 0, 0);
}

// ---------------- scans ------------------------------------------------------
__global__ void k_scan1(const int* __restrict__ cnt, int* __restrict__ rowptr,
                        int* __restrict__ part, float* __restrict__ dis, int n) {
    __shared__ int sums[256];
    int b = blockIdx.x, t = threadIdx.x;
    int base = b * 1024 + t * 4;
    int v0 = (base + 0 < n) ? cnt[base + 0] : 0;
    int v1 = (base + 1 < n) ? cnt[base + 1] : 0;
    int v2 = (base + 2 < n) ? cnt[base + 2] : 0;
    int v3 = (base + 3 < n) ? cnt[base + 3] : 0;
    if (base + 0 < n) dis[base + 0] = rsqrtf((float)v0 + 1.0f);
    if (base + 1 < n) dis[base + 1] = rsqrtf((float)v1 + 1.0f);
    if (base + 2 < n) dis[base + 2] = rsqrtf((float)v2 + 1.0f);
    if (base + 3 < n) dis[base + 3] = rsqrtf((float)v3 + 1.0f);
    int tsum = v0 + v1 + v2 + v3;
    sums[t] = tsum;
    __syncthreads();
    for (int off = 1; off < 256; off <<= 1) {
        int y = (t >= off) ? sums[t - off] : 0;
        __syncthreads();
        sums[t] += y;
        __syncthreads();
    }
    int excl = sums[t] - tsum;
    if (base + 0 < n) rowptr[base + 0] = excl;
    if (base + 1 < n) rowptr[base + 1] = excl + v0;
    if (base + 2 < n) rowptr[base + 2] = excl + v0 + v1;
    if (base + 3 < n) rowptr[base + 3] = excl + v0 + v1 + v2;
    if (t == 255) part[b] = sums[255];
}

// merged scan2+scan3: each block redundantly scans part[] in LDS (nb<=256),
// then adds the block-offset to its rowptr slice. Removes one dispatch.
__global__ void k_scan23(int* __restrict__ rowptr, const int* __restrict__ part,
                         int n, int total, int nb) {
    __shared__ int ps[256];
    int t = threadIdx.x;
    int v = (t < nb) ? part[t] : 0;
    ps[t] = v;
    __syncthreads();
    for (int off = 1; off < 256; off <<= 1) {
        int y = (t >= off) ? ps[t - off] : 0;
        __syncthreads();
        ps[t] += y;
        __syncthreads();
    }
    int incl = ps[t];
    __syncthreads();
    ps[t] = incl - v;           // exclusive
    __syncthreads();
    int i = blockIdx.x * blockDim.x + t;
    if (i < n) rowptr[i] += ps[i >> 10];
    if (i == 0) rowptr[n] = total;
}

// ---------------- merged prep: hist | cvt | transpose ------------------------
struct TArgs {
    const float *W0, *W1, *W2, *W3, *W4;
    f16 *T0, *T1, *T2, *T3, *T4;
};
#define HB   3125
#define CVTB 14375
#define TRB  832
#define NA4  1280000
#define NB4  1920000
#define NC4  480000
struct PrepArgs {
    const int* dst; int* cnt;
    const float *x1, *x2, *x3; f16* xc;
    TArgs t;
};
__global__ __launch_bounds__(256) void k_prep(PrepArgs a) {
    int bid = blockIdx.x, tid = threadIdx.x;
    if (bid < HB) {
        int i = bid * 256 + tid;
        if (i < EE) atomicAdd(&a.cnt[a.dst[i]], 1);
    } else if (bid < HB + CVTB) {
        int i = (bid - HB) * 256 + tid;
        const float* s; int j;
        if (i < NA4) { s = a.x1; j = i; }
        else if (i < NA4 + NB4) { s = a.x2; j = i - NA4; }
        else if (i < NA4 + NB4 + NC4) { s = a.x3; j = i - NA4 - NB4; }
        else return;
        float4 v = reinterpret_cast<const float4*>(s)[j];
        f16x4 r = {(f16)v.x, (f16)v.y, (f16)v.z, (f16)v.w};
        reinterpret_cast<f16x4*>(a.xc)[i] = r;
    } else {
        int i = (bid - HB - CVTB) * 256 + tid;
        const float* W; f16* T; int K, N, j;
        if      (i <  32768) { W = a.t.W0; T = a.t.T0; K = 128; N = 256; j = i; }
        else if (i <  98304) { W = a.t.W1; T = a.t.T1; K = 256; N = 256; j = i - 32768; }
        else if (i < 114688) { W = a.t.W2; T = a.t.T2; K =  64; N = 256; j = i - 98304; }
        else if (i < 180224) { W = a.t.W3; T = a.t.T3; K = 256; N = 256; j = i - 114688; }
        else if (i < 212992) { W = a.t.W4; T = a.t.T4; K = 256; N = 128; j = i - 180224; }
        else return;
        int k = j / N, n = j - k * N;
        T[n * K + k] = (f16)W[j];
    }
}

// ---------------- projection GEMM body (128x128 tile, gload_lds dbuf) -------
template<bool RELU_OUT, bool HAS_BIAS>
__device__ __forceinline__
void hgemm_body(f16* As, f16* Bs,
                const f16* __restrict__ A, const f16* __restrict__ BT,
                const float* __restrict__ bias, f16* __restrict__ C,
                int M, int K, int N, int bx, int by) {
    const int tid = threadIdx.x;
    const int lane = tid & 63;
    const int wid = tid >> 6;
    const int wm = wid & 1, wn = wid >> 1;
    const int bm = bx * 128;
    const int bn = by * 128;
    const int r15 = lane & 15, g = lane >> 4;
    const int sr  = lane >> 2;
    const int chs = (lane & 3) ^ ((lane >> 3) & 3);

    auto stage = [&](int buf, int k0) {
        #pragma unroll
        for (int q = 0; q < 2; ++q) {
            int chunk = wid + q * 4;
            int row = chunk * 16 + sr;
            int ga = bm + row; if (ga >= M) ga = M - 1;
            gload_lds16(A  + (size_t)ga * K + k0 + chs * 8, As + buf * 4096 + chunk * 512);
            gload_lds16(BT + (size_t)(bn + row) * K + k0 + chs * 8, Bs + buf * 4096 + chunk * 512);
        }
    };

    f32x4 acc[4][4] = {};
    const int nsteps = K >> 5;
    stage(0, 0);
    __syncthreads();
    int cur = 0;
    for (int step = 0; step < nsteps; ++step) {
        if (step + 1 < nsteps) stage(cur ^ 1, (step + 1) << 5);
        f16x8 af[4], bf[4];
        const int sl = (g ^ ((r15 >> 1) & 3)) * 8;
        #pragma unroll
        for (int mf = 0; mf < 4; ++mf) {
            int row = wm * 64 + mf * 16 + r15;
            af[mf] = *reinterpret_cast<const f16x8*>(As + cur * 4096 + row * 32 + sl);
        }
        #pragma unroll
        for (int nf = 0; nf < 4; ++nf) {
            int row = wn * 64 + nf * 16 + r15;
            bf[nf] = *reinterpret_cast<const f16x8*>(Bs + cur * 4096 + row * 32 + sl);
        }
        #pragma unroll
        for (int mf = 0; mf < 4; ++mf)
            #pragma unroll
            for (int nf = 0; nf < 4; ++nf)
                acc[mf][nf] = __builtin_amdgcn_mfma_f32_16x16x32_f16(af[mf], bf[nf], acc[mf][nf], 0, 0, 0);
        __syncthreads();
        cur ^= 1;
    }

    #pragma unroll
    for (int mf = 0; mf < 4; ++mf) {
        #pragma unroll
        for (int nf = 0; nf < 4; ++nf) {
            int col = bn + wn * 64 + nf * 16 + r15;
            float bv = HAS_BIAS ? bias[col] : 0.f;
            #pragma unroll
            for (int r = 0; r < 4; ++r) {
                int rowg = bm + wm * 64 + mf * 16 + g * 4 + r;
                if (rowg < M) {
                    float v = acc[mf][nf][r] + bv;
                    if (RELU_OUT) v = fmaxf(v, 0.f);
                    C[(size_t)rowg * N + col] = (f16)v;
                }
            }
        }
    }
}

// ---------------- merged: CSR fill | 3 projections ---------------------------
struct P3 {
    const f16 *a1, *a2, *a3, *t1, *t2, *t3;
    const float *b1, *b2, *b3;
    f16 *o1, *o2, *o3;
    int g1, g2;
};
#define FB 3125
struct FPArgs {
    const int *src, *dst;
    const float* dis;
    const int* rowptr;
    int* cursor;
    int2* e_pairs;
    P3 p;
};
__global__ __launch_bounds__(256) void k_fillproj(FPArgs a) {
    extern __shared__ f16 smem[];
    int bid = blockIdx.x;
    if (bid < FB) {
        int i = bid * 256 + threadIdx.x;
        if (i >= EE) return;
        int s = a.src[i], t = a.dst[i];
        int pos = atomicAdd(&a.cursor[t], 1);
        int2 pr;
        pr.x = s;
        pr.y = __float_as_int(a.dis[s] * a.dis[t]);
        a.e_pairs[a.rowptr[t] + pos] = pr;
    } else {
        int pb = bid - FB;
        int bx = pb >> 1, by = pb & 1;
        if (bx < a.p.g1)
            hgemm_body<false, true>(smem, smem + 8192, a.p.a1, a.p.t1, a.p.b1, a.p.o1, NN1, 128, 256, bx, by);
        else if (bx < a.p.g1 + a.p.g2)
            hgemm_body<false, true>(smem, smem + 8192, a.p.a2, a.p.t2, a.p.b2, a.p.o2, NN2, 256, 256, bx - a.p.g1, by);
        else
            hgemm_body<false, true>(smem, smem + 8192, a.p.a3, a.p.t3, a.p.b3, a.p.o3, NN3, 64, 256, bx - a.p.g1 - a.p.g2, by);
    }
}

// ---------------- FUSED: gather(Âx) -> GEMM1+ReLU -> GEMM2 ------------------
// 512 threads (8 waves), 64 dst nodes/block. Phase 1: R10 geometry (16x32-lane
// groups, 4 rows, f16x8, unroll-4 — measured best) + R14 batched header
// hoisting: both rows' rowptr/dis/self/pair loads issued before either edge
// loop. Serial chain 16 -> 12 latencies. launch_bounds(512,8) pins VGPR<=64
// (m69: occupancy halves AT 64).
__global__ __launch_bounds__(512, 8)
void k_fused(const f16* __restrict__ x16, const float* __restrict__ dis,
             const int* __restrict__ rowptr, const int2* __restrict__ e_pairs,
             const f16* __restrict__ W1T, const float* __restrict__ b1,
             const f16* __restrict__ W2T, f16* __restrict__ hw2, int M) {
    __shared__ f16 P[64 * 256];
    const int tid = threadIdx.x;
    const int lane = tid & 63;
    const int bm = blockIdx.x * 64;

    // ---- phase 1: gather 64 agg-rows into P (2-row batches, hoisted headers)
    {
        const int grp = tid >> 5;     // 0..15
        const int l = tid & 31;
        #pragma unroll
        for (int half = 0; half < 2; ++half) {
            const int rowA = (half * 2 + 0) * 16 + grp;
            const int rowB = (half * 2 + 1) * 16 + grp;
            const int ndA = bm + rowA, ndB = bm + rowB;
            const bool okA = ndA < M, okB = ndB < M;
            const int ncA = okA ? ndA : M - 1, ncB = okB ? ndB : M - 1;
            // hoisted headers: independent loads for BOTH rows issue together
            int r0A = rowptr[ncA], r1A = rowptr[ncA + 1];
            int r0B = rowptr[ncB], r1B = rowptr[ncB + 1];
            float djA = dis[ncA], djB = dis[ncB];
            f16x8 saA = reinterpret_cast<const f16x8*>(x16 + (size_t)ncA * 256)[l];
            f16x8 saB = reinterpret_cast<const f16x8*>(x16 + (size_t)ncB * 256)[l];
            int degA = r1A - r0A, degB = r1B - r0B;
            int siA = 0, siB = 0; float wiA = 0.f, wiB = 0.f;
            if (l < degA) { int2 pr = e_pairs[r0A + l]; siA = pr.x; wiA = __int_as_float(pr.y); }
            if (l < degB) { int2 pr = e_pairs[r0B + l]; siB = pr.x; wiB = __int_as_float(pr.y); }

            // ---- row A
            {
                float av[8];
                float wself = djA * djA;
                #pragma unroll
                for (int k = 0; k < 8; ++k) av[k] = (float)saA[k] * wself;
                int n32 = degA < 32 ? degA : 32;
                int e = 0;
                for (; e + 4 <= n32; e += 4) {
                    int s0 = __shfl(siA, e + 0, 32), s1 = __shfl(siA, e + 1, 32);
                    int s2 = __shfl(siA, e + 2, 32), s3 = __shfl(siA, e + 3, 32);
                    float w0 = __shfl(wiA, e + 0, 32), w1 = __shfl(wiA, e + 1, 32);
                    float w2 = __shfl(wiA, e + 2, 32), w3 = __shfl(wiA, e + 3, 32);
                    f16x8 u0 = reinterpret_cast<const f16x8*>(x16 + (size_t)s0 * 256)[l];
                    f16x8 u1 = reinterpret_cast<const f16x8*>(x16 + (size_t)s1 * 256)[l];
                    f16x8 u2 = reinterpret_cast<const f16x8*>(x16 + (size_t)s2 * 256)[l];
                    f16x8 u3 = reinterpret_cast<const f16x8*>(x16 + (size_t)s3 * 256)[l];
                    #pragma unroll
                    for (int k = 0; k < 8; ++k)
                        av[k] += (float)u0[k] * w0 + (float)u1[k] * w1
                               + (float)u2[k] * w2 + (float)u3[k] * w3;
                }
                for (; e < n32; ++e) {
                    int s0 = __shfl(siA, e, 32);
                    float w0 = __shfl(wiA, e, 32);
                    f16x8 u0 = reinterpret_cast<const f16x8*>(x16 + (size_t)s0 * 256)[l];
                    #pragma unroll
                    for (int k = 0; k < 8; ++k) av[k] += (float)u0[k] * w0;
                }
                for (int e2 = r0A + 32; e2 < r1A; ++e2) {
                    int2 pr = e_pairs[e2];
                    float w0 = __int_as_float(pr.y);
                    f16x8 u0 = reinterpret_cast<const f16x8*>(x16 + (size_t)pr.x * 256)[l];
                    #pragma unroll
                    for (int k = 0; k < 8; ++k) av[k] += (float)u0[k] * w0;
                }
                f16x8 r;
                #pragma unroll
                for (int k = 0; k < 8; ++k) r[k] = okA ? (f16)av[k] : (f16)0.f;
                int slot = (l & 3) ^ ((rowA >> 1) & 3);
                *reinterpret_cast<f16x8*>(P + (l >> 2) * 2048 + rowA * 32 + slot * 8) = r;
            }
            // ---- row B
            {
                float av[8];
                float wself = djB * djB;
                #pragma unroll
                for (int k = 0; k < 8; ++k) av[k] = (float)saB[k] * wself;
                int n32 = degB < 32 ? degB : 32;
                int e = 0;
                for (; e + 4 <= n32; e += 4) {
                    int s0 = __shfl(siB, e + 0, 32), s1 = __shfl(siB, e + 1, 32);
                    int s2 = __shfl(siB, e + 2, 32), s3 = __shfl(siB, e + 3, 32);
                    float w0 = __shfl(wiB, e + 0, 32), w1 = __shfl(wiB, e + 1, 32);
                    float w2 = __shfl(wiB, e + 2, 32), w3 = __shfl(wiB, e + 3, 32);
                    f16x8 u0 = reinterpret_cast<const f16x8*>(x16 + (size_t)s0 * 256)[l];
                    f16x8 u1 = reinterpret_cast<const f16x8*>(x16 + (size_t)s1 * 256)[l];
                    f16x8 u2 = reinterpret_cast<const f16x8*>(x16 + (size_t)s2 * 256)[l];
                    f16x8 u3 = reinterpret_cast<const f16x8*>(x16 + (size_t)s3 * 256)[l];
                    #pragma unroll
                    for (int k = 0; k < 8; ++k)
                        av[k] += (float)u0[k] * w0 + (float)u1[k] * w1
                               + (float)u2[k] * w2 + (float)u3[k] * w3;
                }
                for (; e < n32; ++e) {
                    int s0 = __shfl(siB, e, 32);
                    float w0 = __shfl(wiB, e, 32);
                    f16x8 u0 = reinterpret_cast<const f16x8*>(x16 + (size_t)s0 * 256)[l];
                    #pragma unroll
                    for (int k = 0; k < 8; ++k) av[k] += (float)u0[k] * w0;
                }
                for (int e2 = r0B + 32; e2 < r1B; ++e2) {
                    int2 pr = e_pairs[e2];
                    float w0 = __int_as_float(pr.y);
                    f16x8 u0 = reinterpret_cast<const f16x8*>(x16 + (size_t)pr.x * 256)[l];
                    #pragma unroll
                    for (int k = 0; k < 8; ++k) av[k] += (float)u0[k] * w0;
                }
                f16x8 r;
                #pragma unroll
                for (int k = 0; k < 8; ++k) r[k] = okB ? (f16)av[k] : (f16)0.f;
                int slot = (l & 3) ^ ((rowB >> 1) & 3);
                *reinterpret_cast<f16x8*>(P + (l >> 2) * 2048 + rowB * 32 + slot * 8) = r;
            }
        }
    }
    __syncthreads();

    // ---- phase 2: h = relu(P @ W1 + b1) — wave w owns h cols [w*32, w*32+32)
    const int w = tid >> 6;
    const int r15 = lane & 15, g = lane >> 4;
    f32x4 acc[4][2] = {};
    for (int step = 0; step < 8; ++step) {
        f16x8 af[4], bf[2];
        #pragma unroll
        for (int mf = 0; mf < 4; ++mf) {
            int row = mf * 16 + r15;
            int slot = g ^ ((row >> 1) & 3);
            af[mf] = *reinterpret_cast<const f16x8*>(P + step * 2048 + row * 32 + slot * 8);
        }
        #pragma unroll
        for (int nf = 0; nf < 2; ++nf) {
            int n1 = w * 32 + nf * 16 + r15;
            bf[nf] = *reinterpret_cast<const f16x8*>(W1T + (size_t)n1 * 256 + step * 32 + g * 8);
        }
        #pragma unroll
        for (int mf = 0; mf < 4; ++mf)
            #pragma unroll
            for (int nf = 0; nf < 2; ++nf)
                acc[mf][nf] = __builtin_amdgcn_mfma_f32_16x16x32_f16(af[mf], bf[nf], acc[mf][nf], 0, 0, 0);
    }
    __syncthreads();

    // relu + bias, write h back into P (same swizzled layout)
    #pragma unroll
    for (int nf = 0; nf < 2; ++nf) {
        int col = w * 32 + nf * 16 + r15;
        float bv = b1[col];
        int gp = (col >> 3) & 3, c7 = col & 7;
        #pragma unroll
        for (int mf = 0; mf < 4; ++mf) {
            #pragma unroll
            for (int rr = 0; rr < 4; ++rr) {
                int row = mf * 16 + g * 4 + rr;
                float v = fmaxf(acc[mf][nf][rr] + bv, 0.f);
                int slot = gp ^ ((row >> 1) & 3);
                P[w * 2048 + row * 32 + slot * 8 + c7] = (f16)v;
            }
        }
    }
    __syncthreads();

    // ---- phase 3: out = h @ W2 — wave w owns out cols [w*16, w*16+16)
    f32x4 acc2[4] = {};
    for (int step = 0; step < 8; ++step) {
        f16x8 af[4], bf;
        #pragma unroll
        for (int mf = 0; mf < 4; ++mf) {
            int row = mf * 16 + r15;
            int slot = g ^ ((row >> 1) & 3);
            af[mf] = *reinterpret_cast<const f16x8*>(P + step * 2048 + row * 32 + slot * 8);
        }
        int n2 = w * 16 + r15;
        bf = *reinterpret_cast<const f16x8*>(W2T + (size_t)n2 * 256 + step * 32 + g * 8);
        #pragma unroll
        for (int mf = 0; mf < 4; ++mf)
            acc2[mf] = __builtin_amdgcn_mfma_f32_16x16x32_f16(af[mf], bf, acc2[mf], 0, 0, 0);
    }

    #pragma unroll
    for (int mf = 0; mf < 4; ++mf) {
        int col = w * 16 + r15;
        #pragma unroll
        for (int rr = 0; rr < 4; ++rr) {
            int rowg = bm + mf * 16 + g * 4 + rr;
            if (rowg < M)
                hw2[(size_t)rowg * 128 + col] = (f16)acc2[mf][rr];
        }
    }
}

// ---------------- final gather (D=128, f32 out + bias, unroll-8) ------------
__global__ void k_gather128(const f16* __restrict__ f, const float* __restrict__ dis,
                            const int* __restrict__ rowptr, const int2* __restrict__ e_pairs,
                            const float* __restrict__ bias, float* __restrict__ outb, int n) {
    int node = (int)(((long long)blockIdx.x * blockDim.x + threadIdx.x) >> 5);
    int l = threadIdx.x & 31;
    if (node >= n) return;
    float dj = dis[node];
    int r0 = rowptr[node], r1 = rowptr[node + 1];
    int deg = r1 - r0;
    int si = 0; float wi = 0.f;
    if (l < deg) { int2 p = e_pairs[r0 + l]; si = p.x; wi = __int_as_float(p.y); }
    f16x4 a = reinterpret_cast<const f16x4*>(f + (size_t)node * 128)[l];
    float wsf = dj * dj;
    float acc[4];
    #pragma unroll
    for (int k = 0; k < 4; ++k) acc[k] = (float)a[k] * wsf;
    int n32 = deg < 32 ? deg : 32;
    int e = 0;
    for (; e + 8 <= n32; e += 8) {
        int s[8]; float w[8];
        #pragma unroll
        for (int q = 0; q < 8; ++q) {
            s[q] = __shfl(si, e + q, 32);
            w[q] = __shfl(wi, e + q, 32);
        }
        f16x4 u[8];
        #pragma unroll
        for (int q = 0; q < 8; ++q)
            u[q] = reinterpret_cast<const f16x4*>(f + (size_t)s[q] * 128)[l];
        #pragma unroll
        for (int q = 0; q < 8; ++q)
            #pragma unroll
            for (int k = 0; k < 4; ++k) acc[k] += (float)u[q][k] * w[q];
    }
    for (; e + 4 <= n32; e += 4) {
        int s[4]; float w[4];
        #pragma unroll
        for (int q = 0; q < 4; ++q) {
            s[q] = __shfl(si, e + q, 32);
            w[q] = __shfl(wi, e + q, 32);
        }
        f16x4 u[4];
        #pragma unroll
        for (int q = 0; q < 4; ++q)
            u[q] = reinterpret_cast<const f16x4*>(f + (size_t)s[q] * 128)[l];
        #pragma unroll
        for (int q = 0; q < 4; ++q)
            #pragma unroll
            for (int k = 0; k < 4; ++k) acc[k] += (float)u[q][k] * w[q];
    }
    for (; e < n32; ++e) {
        int s0 = __shfl(si, e, 32);
        float w0 = __shfl(wi, e, 32);
        f16x4 u0 = reinterpret_cast<const f16x4*>(f + (size_t)s0 * 128)[l];
        #pragma unroll
        for (int k = 0; k < 4; ++k) acc[k] += (float)u0[k] * w0;
    }
    for (int e2 = r0 + 32; e2 < r1; ++e2) {
        int2 p = e_pairs[e2];
        float w0 = __int_as_float(p.y);
        f16x4 u0 = reinterpret_cast<const f16x4*>(f + (size_t)p.x * 128)[l];
        #pragma unroll
        for (int k = 0; k < 4; ++k) acc[k] += (float)u0[k] * w0;
    }
    float4 bb = reinterpret_cast<const float4*>(bias)[l];
    float4 r = make_float4(acc[0] + bb.x, acc[1] + bb.y, acc[2] + bb.z, acc[3] + bb.w);
    reinterpret_cast<float4*>(outb + (size_t)node * 128)[l] = r;
}

extern "C" void kernel_launch(void* const* d_in, const int* in_sizes, int n_in,
                              void* d_out, int out_size, void* d_ws, size_t ws_size,
                              hipStream_t stream) {
    const float* x1  = (const float*)d_in[0];
    const float* x2  = (const float*)d_in[1];
    const float* x3  = (const float*)d_in[2];
    const float* Wp1 = (const float*)d_in[3];
    const float* bp1 = (const float*)d_in[4];
    const float* Wp2 = (const float*)d_in[5];
    const float* bp2 = (const float*)d_in[6];
    const float* Wp3 = (const float*)d_in[7];
    const float* bp3 = (const float*)d_in[8];
    const float* W1  = (const float*)d_in[9];
    const float* b1  = (const float*)d_in[10];
    const float* W2  = (const float*)d_in[11];
    const float* b2  = (const float*)d_in[12];
    const int*   ei  = (const int*)d_in[13];
    const int* src = ei;
    const int* dst = ei + EE;
    float* out = (float*)d_out;

    // workspace (~118 MB)
    char* ws = (char*)d_ws;
    size_t off = 0;
    auto alloc = [&](size_t bytes) {
        char* p = ws + off;
        off += (bytes + 511) & ~(size_t)511;
        return p;
    };
    float* dis    = (float*)alloc((size_t)NT * 4);
    int*   cnt    = (int*)alloc((size_t)NT * 4);
    int*   cursor = (int*)alloc((size_t)NT * 4);
    int*   rowptr = (int*)alloc((size_t)(NT + 1) * 4);
    int*   part   = (int*)alloc(256 * 4);
    int2*  e_pairs= (int2*)alloc((size_t)EE * 8);
    f16*   x16    = (f16*)alloc((size_t)NT * 256 * 2);
    f16*   hw216  = (f16*)alloc((size_t)NT * 128 * 2);
    f16*   xc     = (f16*)alloc((size_t)(NN1 * 128 + NN2 * 256 + NN3 * 64) * 2);
    f16*   Wp1T   = (f16*)alloc((size_t)256 * 128 * 2);
    f16*   Wp2T   = (f16*)alloc((size_t)256 * 256 * 2);
    f16*   Wp3T   = (f16*)alloc((size_t)256 * 64 * 2);
    f16*   W1T    = (f16*)alloc((size_t)256 * 256 * 2);
    f16*   W2T    = (f16*)alloc((size_t)128 * 256 * 2);

    f16* x1c = xc;
    f16* x2c = xc + (size_t)NN1 * 128;
    f16* x3c = xc + (size_t)NN1 * 128 + (size_t)NN2 * 256;

    const int nb = cdiv(NT, 1024);

    // 0) zero cnt+cursor (adjacent allocs)
    size_t zspan = (size_t)((char*)rowptr - (char*)cnt);
    hipMemsetAsync(cnt, 0, zspan, stream);

    // 1) merged prep: hist | cvt | transpose
    {
        PrepArgs a;
        a.dst = dst; a.cnt = cnt;
        a.x1 = x1; a.x2 = x2; a.x3 = x3; a.xc = xc;
        a.t = {Wp1, Wp2, Wp3, W1, W2, Wp1T, Wp2T, Wp3T, W1T, W2T};
        k_prep<<<HB + CVTB + TRB, 256, 0, stream>>>(a);
    }

    // 2) scans (rowptr + dis): scan1, then merged scan2+scan3
    k_scan1<<<nb, 256, 0, stream>>>(cnt, rowptr, part, dis, NT);
    k_scan23<<<cdiv(NT, 256), 256, 0, stream>>>(rowptr, part, NT, EE, nb);

    // 3) merged: CSR fill | projections
    {
        FPArgs a;
        a.src = src; a.dst = dst; a.dis = dis; a.rowptr = rowptr;
        a.cursor = cursor; a.e_pairs = e_pairs;
        a.p = {x1c, x2c, x3c, Wp1T, Wp2T, Wp3T, bp1, bp2, bp3,
               x16, x16 + (size_t)NN1 * 256, x16 + (size_t)(NN1 + NN2) * 256,
               cdiv(NN1, 128), cdiv(NN2, 128)};
        int projb = (cdiv(NN1, 128) + cdiv(NN2, 128) + cdiv(NN3, 128)) * 2;
        k_fillproj<<<FB + projb, 256, 32768, stream>>>(a);
    }

    // 4) fused: gather(Âx) -> GEMM1+ReLU -> GEMM2 -> hw216
    k_fused<<<cdiv(NT, 64), 512, 0, stream>>>(x16, dis, rowptr, e_pairs,
                                              W1T, b1, W2T, hw216, NT);

    // 5) out = Â hw216 + b2  (f32)
    k_gather128<<<cdiv(NT * 32, 256), 256, 0, stream>>>(hw216, dis, rowptr, e_pairs, b2, out, NT);
}

// Round 15
// 271.299 us; speedup vs baseline: 1.0134x; 1.0134x over previous
//
#include <hip/hip_runtime.h>
#include <cstddef>

#define NT 100000
#define NN1 40000
#define NN2 30000
#define NN3 30000
#define EE 800000

typedef _Float16 f16;
typedef f16 f16x8 __attribute__((ext_vector_type(8)));
typedef f16 f16x4 __attribute__((ext_vector_type(4)));
typedef float f32x4 __attribute__((ext_vector_type(4)));

static inline int cdiv(int a, int b) { return (a + b - 1) / b; }

// async global->LDS, 16B per lane
__device__ __forceinline__ void gload_lds16(const f16* g, f16* l) {
    __builtin_amdgcn_global_load_lds(
        (const __attribute__((address_space(1))) void*)g,
        (__attribute__((address_space(3))) void*)l, 16, 0, 0);
}

// ---------------- scans ------------------------------------------------------
__global__ void k_scan1(const int* __restrict__ cnt, int* __restrict__ rowptr,
                        int* __restrict__ part, float* __restrict__ dis, int n) {
    __shared__ int sums[256];
    int b = blockIdx.x, t = threadIdx.x;
    int base = b * 1024 + t * 4;
    int v0 = (base + 0 < n) ? cnt[base + 0] : 0;
    int v1 = (base + 1 < n) ? cnt[base + 1] : 0;
    int v2 = (base + 2 < n) ? cnt[base + 2] : 0;
    int v3 = (base + 3 < n) ? cnt[base + 3] : 0;
    if (base + 0 < n) dis[base + 0] = rsqrtf((float)v0 + 1.0f);
    if (base + 1 < n) dis[base + 1] = rsqrtf((float)v1 + 1.0f);
    if (base + 2 < n) dis[base + 2] = rsqrtf((float)v2 + 1.0f);
    if (base + 3 < n) dis[base + 3] = rsqrtf((float)v3 + 1.0f);
    int tsum = v0 + v1 + v2 + v3;
    sums[t] = tsum;
    __syncthreads();
    for (int off = 1; off < 256; off <<= 1) {
        int y = (t >= off) ? sums[t - off] : 0;
        __syncthreads();
        sums[t] += y;
        __syncthreads();
    }
    int excl = sums[t] - tsum;
    if (base + 0 < n) rowptr[base + 0] = excl;
    if (base + 1 < n) rowptr[base + 1] = excl + v0;
    if (base + 2 < n) rowptr[base + 2] = excl + v0 + v1;
    if (base + 3 < n) rowptr[base + 3] = excl + v0 + v1 + v2;
    if (t == 255) part[b] = sums[255];
}

// merged scan2+scan3 (kept from R14 — one fewer dependent dispatch)
__global__ void k_scan23(int* __restrict__ rowptr, const int* __restrict__ part,
                         int n, int total, int nb) {
    __shared__ int ps[256];
    int t = threadIdx.x;
    int v = (t < nb) ? part[t] : 0;
    ps[t] = v;
    __syncthreads();
    for (int off = 1; off < 256; off <<= 1) {
        int y = (t >= off) ? ps[t - off] : 0;
        __syncthreads();
        ps[t] += y;
        __syncthreads();
    }
    int incl = ps[t];
    __syncthreads();
    ps[t] = incl - v;           // exclusive
    __syncthreads();
    int i = blockIdx.x * blockDim.x + t;
    if (i < n) rowptr[i] += ps[i >> 10];
    if (i == 0) rowptr[n] = total;
}

// ---------------- merged prep: hist | cvt | transpose ------------------------
struct TArgs {
    const float *W0, *W1, *W2, *W3, *W4;
    f16 *T0, *T1, *T2, *T3, *T4;
};
#define HB   3125
#define CVTB 14375
#define TRB  832
#define NA4  1280000
#define NB4  1920000
#define NC4  480000
struct PrepArgs {
    const int* dst; int* cnt;
    const float *x1, *x2, *x3; f16* xc;
    TArgs t;
};
__global__ __launch_bounds__(256) void k_prep(PrepArgs a) {
    int bid = blockIdx.x, tid = threadIdx.x;
    if (bid < HB) {
        int i = bid * 256 + tid;
        if (i < EE) atomicAdd(&a.cnt[a.dst[i]], 1);
    } else if (bid < HB + CVTB) {
        int i = (bid - HB) * 256 + tid;
        const float* s; int j;
        if (i < NA4) { s = a.x1; j = i; }
        else if (i < NA4 + NB4) { s = a.x2; j = i - NA4; }
        else if (i < NA4 + NB4 + NC4) { s = a.x3; j = i - NA4 - NB4; }
        else return;
        float4 v = reinterpret_cast<const float4*>(s)[j];
        f16x4 r = {(f16)v.x, (f16)v.y, (f16)v.z, (f16)v.w};
        reinterpret_cast<f16x4*>(a.xc)[i] = r;
    } else {
        int i = (bid - HB - CVTB) * 256 + tid;
        const float* W; f16* T; int K, N, j;
        if      (i <  32768) { W = a.t.W0; T = a.t.T0; K = 128; N = 256; j = i; }
        else if (i <  98304) { W = a.t.W1; T = a.t.T1; K = 256; N = 256; j = i - 32768; }
        else if (i < 114688) { W = a.t.W2; T = a.t.T2; K =  64; N = 256; j = i - 98304; }
        else if (i < 180224) { W = a.t.W3; T = a.t.T3; K = 256; N = 256; j = i - 114688; }
        else if (i < 212992) { W = a.t.W4; T = a.t.T4; K = 256; N = 128; j = i - 180224; }
        else return;
        int k = j / N, n = j - k * N;
        T[n * K + k] = (f16)W[j];
    }
}

// ---------------- projection GEMM body (128x128 tile, gload_lds dbuf) -------
template<bool RELU_OUT, bool HAS_BIAS>
__device__ __forceinline__
void hgemm_body(f16* As, f16* Bs,
                const f16* __restrict__ A, const f16* __restrict__ BT,
                const float* __restrict__ bias, f16* __restrict__ C,
                int M, int K, int N, int bx, int by) {
    const int tid = threadIdx.x;
    const int lane = tid & 63;
    const int wid = tid >> 6;
    const int wm = wid & 1, wn = wid >> 1;
    const int bm = bx * 128;
    const int bn = by * 128;
    const int r15 = lane & 15, g = lane >> 4;
    const int sr  = lane >> 2;
    const int chs = (lane & 3) ^ ((lane >> 3) & 3);

    auto stage = [&](int buf, int k0) {
        #pragma unroll
        for (int q = 0; q < 2; ++q) {
            int chunk = wid + q * 4;
            int row = chunk * 16 + sr;
            int ga = bm + row; if (ga >= M) ga = M - 1;
            gload_lds16(A  + (size_t)ga * K + k0 + chs * 8, As + buf * 4096 + chunk * 512);
            gload_lds16(BT + (size_t)(bn + row) * K + k0 + chs * 8, Bs + buf * 4096 + chunk * 512);
        }
    };

    f32x4 acc[4][4] = {};
    const int nsteps = K >> 5;
    stage(0, 0);
    __syncthreads();
    int cur = 0;
    for (int step = 0; step < nsteps; ++step) {
        if (step + 1 < nsteps) stage(cur ^ 1, (step + 1) << 5);
        f16x8 af[4], bf[4];
        const int sl = (g ^ ((r15 >> 1) & 3)) * 8;
        #pragma unroll
        for (int mf = 0; mf < 4; ++mf) {
            int row = wm * 64 + mf * 16 + r15;
            af[mf] = *reinterpret_cast<const f16x8*>(As + cur * 4096 + row * 32 + sl);
        }
        #pragma unroll
        for (int nf = 0; nf < 4; ++nf) {
            int row = wn * 64 + nf * 16 + r15;
            bf[nf] = *reinterpret_cast<const f16x8*>(Bs + cur * 4096 + row * 32 + sl);
        }
        #pragma unroll
        for (int mf = 0; mf < 4; ++mf)
            #pragma unroll
            for (int nf = 0; nf < 4; ++nf)
                acc[mf][nf] = __builtin_amdgcn_mfma_f32_16x16x32_f16(af[mf], bf[nf], acc[mf][nf], 0, 0, 0);
        __syncthreads();
        cur ^= 1;
    }

    #pragma unroll
    for (int mf = 0; mf < 4; ++mf) {
        #pragma unroll
        for (int nf = 0; nf < 4; ++nf) {
            int col = bn + wn * 64 + nf * 16 + r15;
            float bv = HAS_BIAS ? bias[col] : 0.f;
            #pragma unroll
            for (int r = 0; r < 4; ++r) {
                int rowg = bm + wm * 64 + mf * 16 + g * 4 + r;
                if (rowg < M) {
                    float v = acc[mf][nf][r] + bv;
                    if (RELU_OUT) v = fmaxf(v, 0.f);
                    C[(size_t)rowg * N + col] = (f16)v;
                }
            }
        }
    }
}

// ---------------- merged: CSR fill | 3 projections ---------------------------
struct P3 {
    const f16 *a1, *a2, *a3, *t1, *t2, *t3;
    const float *b1, *b2, *b3;
    f16 *o1, *o2, *o3;
    int g1, g2;
};
#define FB 3125
struct FPArgs {
    const int *src, *dst;
    const float* dis;
    const int* rowptr;
    int* cursor;
    int2* e_pairs;
    P3 p;
};
__global__ __launch_bounds__(256) void k_fillproj(FPArgs a) {
    extern __shared__ f16 smem[];
    int bid = blockIdx.x;
    if (bid < FB) {
        int i = bid * 256 + threadIdx.x;
        if (i >= EE) return;
        int s = a.src[i], t = a.dst[i];
        int pos = atomicAdd(&a.cursor[t], 1);
        int2 pr;
        pr.x = s;
        pr.y = __float_as_int(a.dis[s] * a.dis[t]);
        a.e_pairs[a.rowptr[t] + pos] = pr;
    } else {
        int pb = bid - FB;
        int bx = pb >> 1, by = pb & 1;
        if (bx < a.p.g1)
            hgemm_body<false, true>(smem, smem + 8192, a.p.a1, a.p.t1, a.p.b1, a.p.o1, NN1, 128, 256, bx, by);
        else if (bx < a.p.g1 + a.p.g2)
            hgemm_body<false, true>(smem, smem + 8192, a.p.a2, a.p.t2, a.p.b2, a.p.o2, NN2, 256, 256, bx - a.p.g1, by);
        else
            hgemm_body<false, true>(smem, smem + 8192, a.p.a3, a.p.t3, a.p.b3, a.p.o3, NN3, 64, 256, bx - a.p.g1 - a.p.g2, by);
    }
}

// ---------------- FUSED: gather(Âx) -> GEMM1+ReLU -> GEMM2 ------------------
// R13's measured-best k_fused verbatim: 512 thr (8 waves), 64 nodes/block,
// phase 1 = 16x32-lane groups x 4 rows, f16x8 (16B/lane), unroll-4.
// Probed and rejected: unroll-8 (VGPR cliff), work-stealing (chain serialize),
// header hoisting + launch_bounds(512,8) (null; occ 66% didn't help -> not
// occupancy-limited). This geometry = structural latency floor ~113 µs.
__global__ __launch_bounds__(512)
void k_fused(const f16* __restrict__ x16, const float* __restrict__ dis,
             const int* __restrict__ rowptr, const int2* __restrict__ e_pairs,
             const f16* __restrict__ W1T, const float* __restrict__ b1,
             const f16* __restrict__ W2T, f16* __restrict__ hw2, int M) {
    __shared__ f16 P[64 * 256];
    const int tid = threadIdx.x;
    const int lane = tid & 63;
    const int bm = blockIdx.x * 64;

    // ---- phase 1: gather 64 agg-rows into P
    {
        const int grp = tid >> 5;     // 0..15
        const int l = tid & 31;
        #pragma unroll
        for (int it = 0; it < 4; ++it) {
            int row = it * 16 + grp;
            int node = bm + row;
            float av[8];
            if (node < M) {
                float dj = dis[node];
                int r0 = rowptr[node], r1 = rowptr[node + 1];
                int deg = r1 - r0;
                int si = 0; float wi = 0.f;
                if (l < deg) { int2 pr = e_pairs[r0 + l]; si = pr.x; wi = __int_as_float(pr.y); }
                f16x8 sa = reinterpret_cast<const f16x8*>(x16 + (size_t)node * 256)[l];
                float wself = dj * dj;
                #pragma unroll
                for (int k = 0; k < 8; ++k) av[k] = (float)sa[k] * wself;
                int n32 = deg < 32 ? deg : 32;
                int e = 0;
                for (; e + 4 <= n32; e += 4) {
                    int s0 = __shfl(si, e + 0, 32), s1 = __shfl(si, e + 1, 32);
                    int s2 = __shfl(si, e + 2, 32), s3 = __shfl(si, e + 3, 32);
                    float w0 = __shfl(wi, e + 0, 32), w1 = __shfl(wi, e + 1, 32);
                    float w2 = __shfl(wi, e + 2, 32), w3 = __shfl(wi, e + 3, 32);
                    f16x8 u0 = reinterpret_cast<const f16x8*>(x16 + (size_t)s0 * 256)[l];
                    f16x8 u1 = reinterpret_cast<const f16x8*>(x16 + (size_t)s1 * 256)[l];
                    f16x8 u2 = reinterpret_cast<const f16x8*>(x16 + (size_t)s2 * 256)[l];
                    f16x8 u3 = reinterpret_cast<const f16x8*>(x16 + (size_t)s3 * 256)[l];
                    #pragma unroll
                    for (int k = 0; k < 8; ++k)
                        av[k] += (float)u0[k] * w0 + (float)u1[k] * w1
                               + (float)u2[k] * w2 + (float)u3[k] * w3;
                }
                for (; e < n32; ++e) {
                    int s0 = __shfl(si, e, 32);
                    float w0 = __shfl(wi, e, 32);
                    f16x8 u0 = reinterpret_cast<const f16x8*>(x16 + (size_t)s0 * 256)[l];
                    #pragma unroll
                    for (int k = 0; k < 8; ++k) av[k] += (float)u0[k] * w0;
                }
                for (int e2 = r0 + 32; e2 < r1; ++e2) {       // deg>32 tail (rare)
                    int2 pr = e_pairs[e2];
                    float w0 = __int_as_float(pr.y);
                    f16x8 u0 = reinterpret_cast<const f16x8*>(x16 + (size_t)pr.x * 256)[l];
                    #pragma unroll
                    for (int k = 0; k < 8; ++k) av[k] += (float)u0[k] * w0;
                }
            } else {
                #pragma unroll
                for (int k = 0; k < 8; ++k) av[k] = 0.f;
            }
            f16x8 r;
            #pragma unroll
            for (int k = 0; k < 8; ++k) r[k] = (f16)av[k];
            int slot = (l & 3) ^ ((row >> 1) & 3);
            *reinterpret_cast<f16x8*>(P + (l >> 2) * 2048 + row * 32 + slot * 8) = r;
        }
    }
    __syncthreads();

    // ---- phase 2: h = relu(P @ W1 + b1) — wave w owns h cols [w*32, w*32+32)
    const int w = tid >> 6;
    const int r15 = lane & 15, g = lane >> 4;
    f32x4 acc[4][2] = {};
    for (int step = 0; step < 8; ++step) {
        f16x8 af[4], bf[2];
        #pragma unroll
        for (int mf = 0; mf < 4; ++mf) {
            int row = mf * 16 + r15;
            int slot = g ^ ((row >> 1) & 3);
            af[mf] = *reinterpret_cast<const f16x8*>(P + step * 2048 + row * 32 + slot * 8);
        }
        #pragma unroll
        for (int nf = 0; nf < 2; ++nf) {
            int n1 = w * 32 + nf * 16 + r15;
            bf[nf] = *reinterpret_cast<const f16x8*>(W1T + (size_t)n1 * 256 + step * 32 + g * 8);
        }
        #pragma unroll
        for (int mf = 0; mf < 4; ++mf)
            #pragma unroll
            for (int nf = 0; nf < 2; ++nf)
                acc[mf][nf] = __builtin_amdgcn_mfma_f32_16x16x32_f16(af[mf], bf[nf], acc[mf][nf], 0, 0, 0);
    }
    __syncthreads();

    // relu + bias, write h back into P (same swizzled layout)
    #pragma unroll
    for (int nf = 0; nf < 2; ++nf) {
        int col = w * 32 + nf * 16 + r15;
        float bv = b1[col];
        int gp = (col >> 3) & 3, c7 = col & 7;
        #pragma unroll
        for (int mf = 0; mf < 4; ++mf) {
            #pragma unroll
            for (int rr = 0; rr < 4; ++rr) {
                int row = mf * 16 + g * 4 + rr;
                float v = fmaxf(acc[mf][nf][rr] + bv, 0.f);
                int slot = gp ^ ((row >> 1) & 3);
                P[w * 2048 + row * 32 + slot * 8 + c7] = (f16)v;
            }
        }
    }
    __syncthreads();

    // ---- phase 3: out = h @ W2 — wave w owns out cols [w*16, w*16+16)
    f32x4 acc2[4] = {};
    for (int step = 0; step < 8; ++step) {
        f16x8 af[4], bf;
        #pragma unroll
        for (int mf = 0; mf < 4; ++mf) {
            int row = mf * 16 + r15;
            int slot = g ^ ((row >> 1) & 3);
            af[mf] = *reinterpret_cast<const f16x8*>(P + step * 2048 + row * 32 + slot * 8);
        }
        int n2 = w * 16 + r15;
        bf = *reinterpret_cast<const f16x8*>(W2T + (size_t)n2 * 256 + step * 32 + g * 8);
        #pragma unroll
        for (int mf = 0; mf < 4; ++mf)
            acc2[mf] = __builtin_amdgcn_mfma_f32_16x16x32_f16(af[mf], bf, acc2[mf], 0, 0, 0);
    }

    #pragma unroll
    for (int mf = 0; mf < 4; ++mf) {
        int col = w * 16 + r15;
        #pragma unroll
        for (int rr = 0; rr < 4; ++rr) {
            int rowg = bm + mf * 16 + g * 4 + rr;
            if (rowg < M)
                hw2[(size_t)rowg * 128 + col] = (f16)acc2[mf][rr];
        }
    }
}

// ---------------- final gather (D=128, f32 out + bias, unroll-8) ------------
__global__ void k_gather128(const f16* __restrict__ f, const float* __restrict__ dis,
                            const int* __restrict__ rowptr, const int2* __restrict__ e_pairs,
                            const float* __restrict__ bias, float* __restrict__ outb, int n) {
    int node = (int)(((long long)blockIdx.x * blockDim.x + threadIdx.x) >> 5);
    int l = threadIdx.x & 31;
    if (node >= n) return;
    float dj = dis[node];
    int r0 = rowptr[node], r1 = rowptr[node + 1];
    int deg = r1 - r0;
    int si = 0; float wi = 0.f;
    if (l < deg) { int2 p = e_pairs[r0 + l]; si = p.x; wi = __int_as_float(p.y); }
    f16x4 a = reinterpret_cast<const f16x4*>(f + (size_t)node * 128)[l];
    float wsf = dj * dj;
    float acc[4];
    #pragma unroll
    for (int k = 0; k < 4; ++k) acc[k] = (float)a[k] * wsf;
    int n32 = deg < 32 ? deg : 32;
    int e = 0;
    for (; e + 8 <= n32; e += 8) {
        int s[8]; float w[8];
        #pragma unroll
        for (int q = 0; q < 8; ++q) {
            s[q] = __shfl(si, e + q, 32);
            w[q] = __shfl(wi, e + q, 32);
        }
        f16x4 u[8];
        #pragma unroll
        for (int q = 0; q < 8; ++q)
            u[q] = reinterpret_cast<const f16x4*>(f + (size_t)s[q] * 128)[l];
        #pragma unroll
        for (int q = 0; q < 8; ++q)
            #pragma unroll
            for (int k = 0; k < 4; ++k) acc[k] += (float)u[q][k] * w[q];
    }
    for (; e + 4 <= n32; e += 4) {
        int s[4]; float w[4];
        #pragma unroll
        for (int q = 0; q < 4; ++q) {
            s[q] = __shfl(si, e + q, 32);
            w[q] = __shfl(wi, e + q, 32);
        }
        f16x4 u[4];
        #pragma unroll
        for (int q = 0; q < 4; ++q)
            u[q] = reinterpret_cast<const f16x4*>(f + (size_t)s[q] * 128)[l];
        #pragma unroll
        for (int q = 0; q < 4; ++q)
            #pragma unroll
            for (int k = 0; k < 4; ++k) acc[k] += (float)u[q][k] * w[q];
    }
    for (; e < n32; ++e) {
        int s0 = __shfl(si, e, 32);
        float w0 = __shfl(wi, e, 32);
        f16x4 u0 = reinterpret_cast<const f16x4*>(f + (size_t)s0 * 128)[l];
        #pragma unroll
        for (int k = 0; k < 4; ++k) acc[k] += (float)u0[k] * w0;
    }
    for (int e2 = r0 + 32; e2 < r1; ++e2) {
        int2 p = e_pairs[e2];
        float w0 = __int_as_float(p.y);
        f16x4 u0 = reinterpret_cast<const f16x4*>(f + (size_t)p.x * 128)[l];
        #pragma unroll
        for (int k = 0; k < 4; ++k) acc[k] += (float)u0[k] * w0;
    }
    float4 bb = reinterpret_cast<const float4*>(bias)[l];
    float4 r = make_float4(acc[0] + bb.x, acc[1] + bb.y, acc[2] + bb.z, acc[3] + bb.w);
    reinterpret_cast<float4*>(outb + (size_t)node * 128)[l] = r;
}

extern "C" void kernel_launch(void* const* d_in, const int* in_sizes, int n_in,
                              void* d_out, int out_size, void* d_ws, size_t ws_size,
                              hipStream_t stream) {
    const float* x1  = (const float*)d_in[0];
    const float* x2  = (const float*)d_in[1];
    const float* x3  = (const float*)d_in[2];
    const float* Wp1 = (const float*)d_in[3];
    const float* bp1 = (const float*)d_in[4];
    const float* Wp2 = (const float*)d_in[5];
    const float* bp2 = (const float*)d_in[6];
    const float* Wp3 = (const float*)d_in[7];
    const float* bp3 = (const float*)d_in[8];
    const float* W1  = (const float*)d_in[9];
    const float* b1  = (const float*)d_in[10];
    const float* W2  = (const float*)d_in[11];
    const float* b2  = (const float*)d_in[12];
    const int*   ei  = (const int*)d_in[13];
    const int* src = ei;
    const int* dst = ei + EE;
    float* out = (float*)d_out;

    // workspace (~118 MB)
    char* ws = (char*)d_ws;
    size_t off = 0;
    auto alloc = [&](size_t bytes) {
        char* p = ws + off;
        off += (bytes + 511) & ~(size_t)511;
        return p;
    };
    float* dis    = (float*)alloc((size_t)NT * 4);
    int*   cnt    = (int*)alloc((size_t)NT * 4);
    int*   cursor = (int*)alloc((size_t)NT * 4);
    int*   rowptr = (int*)alloc((size_t)(NT + 1) * 4);
    int*   part   = (int*)alloc(256 * 4);
    int2*  e_pairs= (int2*)alloc((size_t)EE * 8);
    f16*   x16    = (f16*)alloc((size_t)NT * 256 * 2);
    f16*   hw216  = (f16*)alloc((size_t)NT * 128 * 2);
    f16*   xc     = (f16*)alloc((size_t)(NN1 * 128 + NN2 * 256 + NN3 * 64) * 2);
    f16*   Wp1T   = (f16*)alloc((size_t)256 * 128 * 2);
    f16*   Wp2T   = (f16*)alloc((size_t)256 * 256 * 2);
    f16*   Wp3T   = (f16*)alloc((size_t)256 * 64 * 2);
    f16*   W1T    = (f16*)alloc((size_t)256 * 256 * 2);
    f16*   W2T    = (f16*)alloc((size_t)128 * 256 * 2);

    f16* x1c = xc;
    f16* x2c = xc + (size_t)NN1 * 128;
    f16* x3c = xc + (size_t)NN1 * 128 + (size_t)NN2 * 256;

    const int nb = cdiv(NT, 1024);

    // 0) zero cnt+cursor (adjacent allocs)
    size_t zspan = (size_t)((char*)rowptr - (char*)cnt);
    hipMemsetAsync(cnt, 0, zspan, stream);

    // 1) merged prep: hist | cvt | transpose
    {
        PrepArgs a;
        a.dst = dst; a.cnt = cnt;
        a.x1 = x1; a.x2 = x2; a.x3 = x3; a.xc = xc;
        a.t = {Wp1, Wp2, Wp3, W1, W2, Wp1T, Wp2T, Wp3T, W1T, W2T};
        k_prep<<<HB + CVTB + TRB, 256, 0, stream>>>(a);
    }

    // 2) scans (rowptr + dis): scan1, then merged scan2+scan3
    k_scan1<<<nb, 256, 0, stream>>>(cnt, rowptr, part, dis, NT);
    k_scan23<<<cdiv(NT, 256), 256, 0, stream>>>(rowptr, part, NT, EE, nb);

    // 3) merged: CSR fill | projections
    {
        FPArgs a;
        a.src = src; a.dst = dst; a.dis = dis; a.rowptr = rowptr;
        a.cursor = cursor; a.e_pairs = e_pairs;
        a.p = {x1c, x2c, x3c, Wp1T, Wp2T, Wp3T, bp1, bp2, bp3,
               x16, x16 + (size_t)NN1 * 256, x16 + (size_t)(NN1 + NN2) * 256,
               cdiv(NN1, 128), cdiv(NN2, 128)};
        int projb = (cdiv(NN1, 128) + cdiv(NN2, 128) + cdiv(NN3, 128)) * 2;
        k_fillproj<<<FB + projb, 256, 32768, stream>>>(a);
    }

    // 4) fused: gather(Âx) -> GEMM1+ReLU -> GEMM2 -> hw216
    k_fused<<<cdiv(NT, 64), 512, 0, stream>>>(x16, dis, rowptr, e_pairs,
                                              W1T, b1, W2T, hw216, NT);

    // 5) out = Â hw216 + b2  (f32)
    k_gather128<<<cdiv(NT * 32, 256), 256, 0, stream>>>(hw216, dis, rowptr, e_pairs, b2, out, NT);
}